// Round 13
// baseline (388.380 us; speedup 1.0000x reference)
//
#include <hip/hip_runtime.h>
#include <hip/hip_bf16.h>

#define NN 100000
#define NE 1000000
#define MPAD 100096   // 1564*64
#define MT64  1564    // 64-row m-tiles
#define MTP64 1568    // padded (8*196)
#define NDB   ((NE + 255) / 256) // degree blocks
#define NCB   (MPAD / 8)         // cvt blocks
#define NPERS 2560               // persistent blocks (256 CU x 10 @16KB LDS)

typedef __attribute__((ext_vector_type(8))) short bf16x8;
typedef __attribute__((ext_vector_type(4))) float f32x4;
typedef __attribute__((ext_vector_type(2))) float f32x2;
typedef __attribute__((ext_vector_type(8))) unsigned short us8;

static __device__ __forceinline__ float bf2f(unsigned short u){
  unsigned int x = ((unsigned int)u) << 16;
  return __uint_as_float(x);
}
static __device__ __forceinline__ unsigned short f2bf(float f){
  unsigned int x = __float_as_uint(f);
  unsigned int r = (x + 0x7fffu + ((x >> 16) & 1u)) >> 16;
  return (unsigned short)r;
}
static __device__ __forceinline__ void addv(float* acc, us8 v){
  #pragma unroll
  for (int k = 0; k < 8; k++) acc[k] += bf2f(v[k]);
}
// fp8 e4m3fn encode: RNE, saturate 448, denormals handled
static __device__ __forceinline__ unsigned char f2fp8(float f){
  unsigned int u = __float_as_uint(f);
  unsigned int s = (u >> 24) & 0x80u;
  float av = fabsf(f);
  if (av >= 448.f) return (unsigned char)(s | 0x7Eu);
  if (av < 0.015625f){
    int m = (int)(av * 512.0f + 0.5f);
    return (unsigned char)(s | (unsigned)m);
  }
  unsigned int au = u & 0x7FFFFFFFu;
  unsigned int r = au + 0x7FFFFu + ((au >> 20) & 1u);
  return (unsigned char)(s | ((r >> 20) - 960u));
}
#if !__has_builtin(__builtin_amdgcn_cvt_pk_f32_fp8)
static __device__ __forceinline__ float fp8tof(unsigned char b){
  unsigned int s = ((unsigned int)(b & 0x80u)) << 24;
  unsigned int e = (b >> 3) & 0xFu, m = b & 7u;
  float v = (e == 0) ? ((float)m * 0.001953125f)
                     : __uint_as_float(((e + 120u) << 23) | (m << 20));
  return __uint_as_float(__float_as_uint(v) | s);
}
#endif
static __device__ __forceinline__ void addq(float* acc, uint2 v){
#if __has_builtin(__builtin_amdgcn_cvt_pk_f32_fp8)
  f32x2 p0 = __builtin_amdgcn_cvt_pk_f32_fp8((int)v.x, false);
  f32x2 p1 = __builtin_amdgcn_cvt_pk_f32_fp8((int)v.x, true);
  f32x2 p2 = __builtin_amdgcn_cvt_pk_f32_fp8((int)v.y, false);
  f32x2 p3 = __builtin_amdgcn_cvt_pk_f32_fp8((int)v.y, true);
  acc[0] += p0[0]; acc[1] += p0[1]; acc[2] += p1[0]; acc[3] += p1[1];
  acc[4] += p2[0]; acc[5] += p2[1]; acc[6] += p3[0]; acc[7] += p3[1];
#else
  unsigned int a = v.x, b = v.y;
  acc[0] += fp8tof(a & 0xFF);         acc[1] += fp8tof((a >> 8) & 0xFF);
  acc[2] += fp8tof((a >> 16) & 0xFF); acc[3] += fp8tof(a >> 24);
  acc[4] += fp8tof(b & 0xFF);         acc[5] += fp8tof((b >> 8) & 0xFF);
  acc[6] += fp8tof((b >> 16) & 0xFF); acc[7] += fp8tof(b >> 24);
#endif
}
static __device__ __forceinline__ void gld16(const void* g, void* l){
  __builtin_amdgcn_global_load_lds((const __attribute__((address_space(1))) void*)g,
                                   (__attribute__((address_space(3))) void*)l, 16, 0, 0);
}

// ---------------- Fused: degree || cvt || prep_w (all independent) ----------------

__global__ __launch_bounds__(256)
void k_dc(const int* __restrict__ dst, int* __restrict__ cnt,
          const float* __restrict__ x, unsigned short* __restrict__ xb,
          const float* __restrict__ W1l, const float* __restrict__ W1r,
          const float* __restrict__ W2l, const float* __restrict__ W2r,
          unsigned short* __restrict__ Bt1, unsigned short* __restrict__ Bt2)
{
  const int bid = blockIdx.x, t = threadIdx.x;
  int role, idx;
  if (bid < 2 * NDB){
    role = bid & 1;               // 1=degree, 0=cvt (interleaved -> concurrent)
    idx = bid >> 1;
  } else if (bid < NDB + NCB){
    role = 0; idx = bid - NDB;
  } else {
    role = 2; idx = bid - NDB - NCB;
  }

  if (role == 1){
    int e = idx * 256 + t;
    if (e < NE) atomicAdd(&cnt[dst[e]], 1);
  } else if (role == 0){
    size_t i = ((size_t)idx * 256 + t) * 8;
    if (i >= (size_t)MPAD * 256) return;
    int row = (int)(i >> 8);
    us8 o;
    if (row < NN){
      const float4* p = (const float4*)(x + i);
      float4 a = p[0], b = p[1];
      o[0]=f2bf(a.x); o[1]=f2bf(a.y); o[2]=f2bf(a.z); o[3]=f2bf(a.w);
      o[4]=f2bf(b.x); o[5]=f2bf(b.y); o[6]=f2bf(b.z); o[7]=f2bf(b.w);
    } else {
      #pragma unroll
      for (int j = 0; j < 8; j++) o[j] = 0;
    }
    *(us8*)(xb + i) = o;
  } else {
    int i = idx * 256 + t;
    if (i < 512 * 256){
      int n = i >> 8, k = i & 255;
      float v = (n < 256) ? W1l[k * 256 + n] : W1r[k * 256 + (n - 256)];
      Bt1[n * 256 + k] = f2bf(v);
    }
    if (i < 256 * 256){
      int n = i >> 8, k = i & 255;
      float v = (n < 128) ? W2l[k * 128 + n] : W2r[k * 128 + (n - 128)];
      Bt2[n * 256 + k] = f2bf(v);
    }
  }
}

// ---------------- CSR scan kernels ----------------

__global__ void k_chunk_sum(const int* __restrict__ cnt, int* __restrict__ partials, int N){
  __shared__ int sw[16];
  int b = blockIdx.x, t = threadIdx.x;
  int i = b * 1024 + t;
  int v = (i < N) ? cnt[i] : 0;
  #pragma unroll
  for (int off = 32; off; off >>= 1) v += __shfl_xor(v, off);
  int lane = t & 63, w = t >> 6;
  if (lane == 0) sw[w] = v;
  __syncthreads();
  if (t < 16){
    int s = sw[t];
    #pragma unroll
    for (int off = 8; off; off >>= 1) s += __shfl_xor(s, off);
    if (t == 0) partials[b] = s;
  }
}

__global__ void k_chunk_scan(const int* __restrict__ cnt, const int* __restrict__ partials,
                             int nchunk,
                             int* __restrict__ offs, int* __restrict__ cursor,
                             float* __restrict__ deginv, int N){
  __shared__ int sd[1024];
  __shared__ int sp[128];
  int b = blockIdx.x, t = threadIdx.x;
  if (t < 128) sp[t] = (t < b && t < nchunk) ? partials[t] : 0;
  int i = b * 1024 + t;
  int v = (i < N) ? cnt[i] : 0;
  sd[t] = v;
  __syncthreads();
  #pragma unroll
  for (int off = 64; off; off >>= 1){
    if (t < off) sp[t] += sp[t + off];
    __syncthreads();
  }
  for (int off = 1; off < 1024; off <<= 1){
    int x = (t >= off) ? sd[t - off] : 0;
    __syncthreads();
    sd[t] += x;
    __syncthreads();
  }
  if (i < N){
    int excl = sp[0] + sd[t] - v;
    offs[i] = excl;
    cursor[i] = excl;
    deginv[i] = (v > 0) ? (1.0f / (float)v) : 0.0f;
  }
}

// ---------------- gemm1 tile body (single-wave 64x64, barrier-free) ----------------

static __device__ __forceinline__
void gemm_tile(const unsigned short* __restrict__ A,
               const unsigned short* __restrict__ Bt,
               unsigned short* lA, unsigned short* lB,
               int lane, int m0, int n0,
               f32x4 (*acc)[4])
{
  const int srow = lane >> 3;
  const int sc   = (lane & 7) ^ ((lane >> 3) & 7);
  for (int kt = 0; kt < 4; ++kt){
    asm volatile("s_waitcnt lgkmcnt(0)" ::: "memory");
    #pragma unroll
    for (int s = 0; s < 8; ++s){
      int row = s * 8 + srow;
      gld16(A  + (size_t)(m0 + row) * 256 + kt * 64 + sc * 8, &lA[s * 512]);
      gld16(Bt + (size_t)(n0 + row) * 256 + kt * 64 + sc * 8, &lB[s * 512]);
    }
    asm volatile("s_waitcnt vmcnt(0)" ::: "memory");
    __builtin_amdgcn_sched_barrier(0);
    #pragma unroll
    for (int ks = 0; ks < 2; ++ks){
      bf16x8 av[4], bv[4];
      const int kc = ks * 4 + (lane >> 4);
      #pragma unroll
      for (int m = 0; m < 4; m++){
        int r = m * 16 + (lane & 15);
        av[m] = *(const bf16x8*)&lA[r * 64 + ((kc ^ (r & 7)) << 3)];
      }
      #pragma unroll
      for (int n = 0; n < 4; n++){
        int c = n * 16 + (lane & 15);
        bv[n] = *(const bf16x8*)&lB[c * 64 + ((kc ^ (c & 7)) << 3)];
      }
      #pragma unroll
      for (int m = 0; m < 4; m++)
        #pragma unroll
        for (int n = 0; n < 4; n++)
          acc[m][n] = __builtin_amdgcn_mfma_f32_16x16x32_bf16(av[m], bv[n], acc[m][n], 0, 0, 0);
    }
  }
}

// ---------------- Fused persistent: CSR fill || GEMM layer 1 ----------------
// NPERS blocks (10/CU at 16KB LDS). Role by (bid&15)<8 so both roles hit all
// XCDs and gemm keeps idx&7 == bid&7 == XCD residue. Each gemm block loops
// ~10 tiles (j strided by 160); each fill block loops ~12 edge-windows.

__global__ __launch_bounds__(64)
void k_fg(const unsigned short* __restrict__ A,
          const unsigned short* __restrict__ Bt,
          unsigned short* __restrict__ R1,
          unsigned char* __restrict__ Q8,
          const int* __restrict__ src, const int* __restrict__ dst,
          int* __restrict__ cursor, int* __restrict__ csr)
{
  __shared__ __align__(16) unsigned short lA[64 * 64];  // 8KB
  __shared__ __align__(16) unsigned short lB[64 * 64];  // 8KB
  const int bid = blockIdx.x;
  const int lane = threadIdx.x & 63;
  const int idx = ((bid >> 4) << 3) + (bid & 7);   // [0, NPERS/2)

  if ((bid & 15) >= 8){
    // fill role: windows idx, idx+1280, ...
    for (int e = idx * 64 + lane; e < NE; e += (NPERS / 2) * 64){
      int p = atomicAdd(&cursor[dst[e]], 1);
      csr[p] = src[e];
    }
    return;
  }

  // gemm role
  const int xcd = idx & 7;
  const int jb  = idx >> 3;            // [0,160)
  for (int j = jb; j < MTP64; j += NPERS / 16){
    const int mt = xcd * (MTP64 / 8) + (j >> 3);
    if (mt >= MT64) continue;
    const int nt = j & 7;
    const int m0 = mt * 64;
    const int n0 = nt * 64;

    f32x4 acc[4][4] = {};
    gemm_tile(A, Bt, lA, lB, lane, m0, n0, acc);

    const int crow0 = m0 + (lane >> 4) * 4;
    const int ccol0 = n0 + (lane & 15);
    if (n0 < 256){
      #pragma unroll
      for (int m = 0; m < 4; m++){
        #pragma unroll
        for (int r = 0; r < 4; r++){
          size_t rowoff = (size_t)(crow0 + m * 16 + r) * 256;
          #pragma unroll
          for (int n = 0; n < 4; n++)
            Q8[rowoff + ccol0 + n * 16] = f2fp8(acc[m][n][r]);
        }
      }
    } else {
      const int cbase = ccol0 - 256;
      #pragma unroll
      for (int m = 0; m < 4; m++){
        #pragma unroll
        for (int r = 0; r < 4; r++){
          size_t rowoff = (size_t)(crow0 + m * 16 + r) * 256;
          #pragma unroll
          for (int n = 0; n < 4; n++)
            R1[rowoff + cbase + n * 16] = f2bf(acc[m][n][r]);
        }
      }
    }
  }
}

// ---------------- GEMM layer 2 (persistent, single-wave, barrier-free) ----------------

template<int NTL2>
__global__ __launch_bounds__(64)
void k_gemm(const unsigned short* __restrict__ A,
            const unsigned short* __restrict__ Bt,
            unsigned short* __restrict__ C)
{
  __shared__ __align__(16) unsigned short lA[64 * 64];
  __shared__ __align__(16) unsigned short lB[64 * 64];
  const int bid = blockIdx.x;
  const int lane = threadIdx.x & 63;
  const int xcd = bid & 7;
  const int jb  = bid >> 3;
  const int jstride = NPERS / 8;
  const int JTOT = (MTP64 / 8) * (1 << NTL2);
  const int Nout = 64 << NTL2;

  for (int j = jb; j < JTOT; j += jstride){
    const int mt = xcd * (MTP64 / 8) + (j >> NTL2);
    if (mt >= MT64) continue;
    const int nt = j & ((1 << NTL2) - 1);
    const int m0 = mt * 64;
    const int n0 = nt * 64;

    f32x4 acc[4][4] = {};
    gemm_tile(A, Bt, lA, lB, lane, m0, n0, acc);

    const int crow0 = m0 + (lane >> 4) * 4;
    const int ccol0 = n0 + (lane & 15);
    #pragma unroll
    for (int m = 0; m < 4; m++){
      #pragma unroll
      for (int r = 0; r < 4; r++){
        size_t rowoff = (size_t)(crow0 + m * 16 + r) * Nout;
        #pragma unroll
        for (int n = 0; n < 4; n++)
          C[rowoff + ccol0 + n * 16] = f2bf(acc[m][n][r]);
      }
    }
  }
}

// ---------------- Aggregation 1: h = relu(deginv*agg(q1_fp8) + r1 + b1) ----------------

__global__ void k_agg1(const unsigned char* __restrict__ Q8,
                       const unsigned short* __restrict__ R1,
                       const float* __restrict__ b1,
                       const int* __restrict__ offs, const int* __restrict__ cnt,
                       const float* __restrict__ deginv,
                       const int* __restrict__ csr,
                       unsigned short* __restrict__ h, int N)
{
  int wv = threadIdx.x >> 6, lane = threadIdx.x & 63;
  int n = blockIdx.x * 4 + wv;
  if (n >= N) return;
  int beg = offs[n], d = cnt[n];
  const int g = lane >> 5;
  const int cl = lane & 31;
  const unsigned char* Qb = Q8 + cl * 8;

  float acc[8];
  #pragma unroll
  for (int k = 0; k < 8; k++) acc[k] = 0.f;

  for (int w0 = 0; w0 < d; w0 += 64){
    int wlen = min(d - w0, 64);
    int idx = 0;
    if (lane < wlen) idx = csr[beg + w0 + lane];
    int nIter = (wlen + 15) >> 4;
    for (int t = 0; t < nIter; t++){
      int e0 = t * 16 + g;
      int s0 = __shfl(idx, e0);
      int s1 = __shfl(idx, e0 + 2);
      int s2 = __shfl(idx, e0 + 4);
      int s3 = __shfl(idx, e0 + 6);
      int s4 = __shfl(idx, e0 + 8);
      int s5 = __shfl(idx, e0 + 10);
      int s6 = __shfl(idx, e0 + 12);
      int s7 = __shfl(idx, e0 + 14);
      uint2 v0 = *(const uint2*)(Qb + (size_t)s0 * 256);
      uint2 v1 = *(const uint2*)(Qb + (size_t)s1 * 256);
      uint2 v2 = *(const uint2*)(Qb + (size_t)s2 * 256);
      uint2 v3 = *(const uint2*)(Qb + (size_t)s3 * 256);
      uint2 v4 = *(const uint2*)(Qb + (size_t)s4 * 256);
      uint2 v5 = *(const uint2*)(Qb + (size_t)s5 * 256);
      uint2 v6 = *(const uint2*)(Qb + (size_t)s6 * 256);
      uint2 v7 = *(const uint2*)(Qb + (size_t)s7 * 256);
      if (e0 < wlen)      addq(acc, v0);
      if (e0 + 2 < wlen)  addq(acc, v1);
      if (e0 + 4 < wlen)  addq(acc, v2);
      if (e0 + 6 < wlen)  addq(acc, v3);
      if (e0 + 8 < wlen)  addq(acc, v4);
      if (e0 + 10 < wlen) addq(acc, v5);
      if (e0 + 12 < wlen) addq(acc, v6);
      if (e0 + 14 < wlen) addq(acc, v7);
    }
  }
  #pragma unroll
  for (int k = 0; k < 8; k++) acc[k] += __shfl_xor(acc[k], 32);

  if (lane < 32){
    float di = deginv[n];
    us8 rv = *(const us8*)(R1 + (size_t)n * 256 + cl * 8);
    float4 b0 = *(const float4*)(b1 + cl * 8);
    float4 b4 = *(const float4*)(b1 + cl * 8 + 4);
    float bb[8] = {b0.x, b0.y, b0.z, b0.w, b4.x, b4.y, b4.z, b4.w};
    us8 o;
    #pragma unroll
    for (int k = 0; k < 8; k++)
      o[k] = f2bf(fmaxf(acc[k] * di + bf2f(rv[k]) + bb[k], 0.f));
    *(us8*)(h + (size_t)n * 256 + cl * 8) = o;
  }
}

// ---------------- Aggregation 2 + classifier + log_softmax (fused, bf16) ----------------

__global__ void k_agg2cls(const unsigned short* __restrict__ C2,
                          const float* __restrict__ b2,
                          const float* __restrict__ Wc,
                          const float* __restrict__ bc,
                          const int* __restrict__ offs, const int* __restrict__ cnt,
                          const float* __restrict__ deginv,
                          const int* __restrict__ csr,
                          float* __restrict__ out, int N)
{
  int wv = threadIdx.x >> 6, lane = threadIdx.x & 63;
  int n = blockIdx.x * 4 + wv;
  if (n >= N) return;
  int beg = offs[n], d = cnt[n];
  const int g = lane >> 4;
  const int cl = lane & 15;

  float acc[8];
  #pragma unroll
  for (int k = 0; k < 8; k++) acc[k] = 0.f;

  for (int w0 = 0; w0 < d; w0 += 64){
    int wlen = min(d - w0, 64);
    int idx = 0;
    if (lane < wlen) idx = csr[beg + w0 + lane];
    int nIter = (wlen + 31) >> 5;
    for (int t = 0; t < nIter; t++){
      int e0 = t * 32 + g;
      int s0 = __shfl(idx, e0);
      int s1 = __shfl(idx, e0 + 4);
      int s2 = __shfl(idx, e0 + 8);
      int s3 = __shfl(idx, e0 + 12);
      int s4 = __shfl(idx, e0 + 16);
      int s5 = __shfl(idx, e0 + 20);
      int s6 = __shfl(idx, e0 + 24);
      int s7 = __shfl(idx, e0 + 28);
      us8 v0 = *(const us8*)(C2 + (size_t)s0 * 256 + cl * 8);
      us8 v1 = *(const us8*)(C2 + (size_t)s1 * 256 + cl * 8);
      us8 v2 = *(const us8*)(C2 + (size_t)s2 * 256 + cl * 8);
      us8 v3 = *(const us8*)(C2 + (size_t)s3 * 256 + cl * 8);
      us8 v4 = *(const us8*)(C2 + (size_t)s4 * 256 + cl * 8);
      us8 v5 = *(const us8*)(C2 + (size_t)s5 * 256 + cl * 8);
      us8 v6 = *(const us8*)(C2 + (size_t)s6 * 256 + cl * 8);
      us8 v7 = *(const us8*)(C2 + (size_t)s7 * 256 + cl * 8);
      if (e0 < wlen)      addv(acc, v0);
      if (e0 + 4 < wlen)  addv(acc, v1);
      if (e0 + 8 < wlen)  addv(acc, v2);
      if (e0 + 12 < wlen) addv(acc, v3);
      if (e0 + 16 < wlen) addv(acc, v4);
      if (e0 + 20 < wlen) addv(acc, v5);
      if (e0 + 24 < wlen) addv(acc, v6);
      if (e0 + 28 < wlen) addv(acc, v7);
    }
  }
  #pragma unroll
  for (int k = 0; k < 8; k++){
    acc[k] += __shfl_xor(acc[k], 16);
    acc[k] += __shfl_xor(acc[k], 32);
  }

  float di = deginv[n];
  us8 rv = *(const us8*)(C2 + (size_t)n * 256 + 128 + cl * 8);
  float4 b0 = *(const float4*)(b2 + cl * 8);
  float4 b4 = *(const float4*)(b2 + cl * 8 + 4);
  float bb[8] = {b0.x, b0.y, b0.z, b0.w, b4.x, b4.y, b4.z, b4.w};
  float p0 = 0.f, p1 = 0.f;
  #pragma unroll
  for (int k = 0; k < 8; k += 2){
    float h0 = fmaxf(acc[k]     * di + bf2f(rv[k])     + bb[k],     0.f);
    float h1 = fmaxf(acc[k + 1] * di + bf2f(rv[k + 1]) + bb[k + 1], 0.f);
    float4 w = *(const float4*)(Wc + (cl * 8 + k) * 2);
    p0 += h0 * w.x + h1 * w.z;
    p1 += h0 * w.y + h1 * w.w;
  }
  #pragma unroll
  for (int off = 8; off; off >>= 1){
    p0 += __shfl_xor(p0, off);
    p1 += __shfl_xor(p1, off);
  }
  if (lane == 0){
    float z0 = p0 + bc[0], z1 = p1 + bc[1];
    float m = fmaxf(z0, z1);
    float lse = m + logf(expf(z0 - m) + expf(z1 - m));
    out[(size_t)n * 2 + 0] = z0 - lse;
    out[(size_t)n * 2 + 1] = z1 - lse;
  }
}

// ---------------- host launch ----------------

extern "C" void kernel_launch(void* const* d_in, const int* in_sizes, int n_in,
                              void* d_out, int out_size, void* d_ws, size_t ws_size,
                              hipStream_t stream)
{
  const float* x   = (const float*)d_in[0];
  const int*   ei  = (const int*)d_in[1];
  const float* W1l = (const float*)d_in[2];
  const float* W1r = (const float*)d_in[3];
  const float* b1  = (const float*)d_in[4];
  const float* W2l = (const float*)d_in[5];
  const float* W2r = (const float*)d_in[6];
  const float* b2  = (const float*)d_in[7];
  const float* Wc  = (const float*)d_in[8];
  const float* bc  = (const float*)d_in[9];
  float* out = (float*)d_out;

  const int N = NN, E = NE;
  const int* src = ei;
  const int* dst = ei + E;

  char* ws = (char*)d_ws;
  size_t off = 0;
  auto alloc = [&](size_t bytes) -> void* {
    void* p = ws + off;
    off += (bytes + 255) & ~(size_t)255;
    return p;
  };
  int*   cnt      = (int*)alloc((size_t)N * 4);
  int*   offs     = (int*)alloc((size_t)N * 4);
  int*   cursor   = (int*)alloc((size_t)N * 4);
  float* deginv   = (float*)alloc((size_t)N * 4);
  int*   partials = (int*)alloc(1024);
  int*   csr      = (int*)alloc((size_t)E * 4);
  unsigned short* Bt1 = (unsigned short*)alloc((size_t)512 * 256 * 2);
  unsigned short* Bt2 = (unsigned short*)alloc((size_t)256 * 256 * 2);
  unsigned short* xb  = (unsigned short*)alloc((size_t)MPAD * 256 * 2);
  unsigned char*  Q8  = (unsigned char*)alloc((size_t)MPAD * 256);
  unsigned short* R1  = (unsigned short*)alloc((size_t)MPAD * 256 * 2);

  unsigned short* h  = xb;   // alias: xb dead after gemm1
  unsigned short* C2 = R1;   // alias: R1 dead after agg1

  (void)in_sizes; (void)n_in; (void)out_size; (void)ws_size;

  hipMemsetAsync(cnt, 0, (size_t)N * 4, stream);

  // degree || cvt || prep_w
  k_dc<<<NDB + NCB + 512, 256, 0, stream>>>(dst, cnt, x, xb, W1l, W1r, W2l, W2r, Bt1, Bt2);

  int nchunk = (N + 1023) / 1024;
  k_chunk_sum<<<nchunk, 1024, 0, stream>>>(cnt, partials, N);
  k_chunk_scan<<<nchunk, 1024, 0, stream>>>(cnt, partials, nchunk, offs, cursor, deginv, N);

  // persistent CSR fill || GEMM layer 1
  k_fg<<<NPERS, 64, 0, stream>>>(xb, Bt1, R1, Q8, src, dst, cursor, csr);

  k_agg1<<<N / 4, 256, 0, stream>>>(Q8, R1, b1, offs, cnt, deginv, csr, h, N);

  // layer 2 (persistent)
  k_gemm<2><<<NPERS, 64, 0, stream>>>(h, Bt2, C2);
  k_agg2cls<<<N / 4, 256, 0, stream>>>(C2, b2, Wc, bc, offs, cnt, deginv, csr, out, N);
}

// Round 14
// 306.555 us; speedup vs baseline: 1.2669x; 1.2669x over previous
//
#include <hip/hip_runtime.h>
#include <hip/hip_bf16.h>

#define NN 100000
#define NE 1000000
#define MPAD 100096   // 1564*64
#define MT64  1564    // 64-row m-tiles
#define MTP64 1568    // padded (8*196)
#define NG1   (MTP64 * 8)        // 12544 gemm1 tile-blocks
#define NDB   ((NE + 255) / 256) // degree blocks
#define NCB   (MPAD / 8)         // cvt blocks
#define CSZ   512                // fill chunk (edges)
#define NCHK  ((NE + CSZ - 1) / CSZ)   // 1954 chunks
#define CINT  ((2 * NG1) / 16)   // 1568 chunks covered by interleaved region
#define NRES  (NN / 8)           // 12500 nodes per XCD residue

typedef __attribute__((ext_vector_type(8))) short bf16x8;
typedef __attribute__((ext_vector_type(4))) float f32x4;
typedef __attribute__((ext_vector_type(2))) float f32x2;
typedef __attribute__((ext_vector_type(8))) unsigned short us8;

static __device__ __forceinline__ float bf2f(unsigned short u){
  unsigned int x = ((unsigned int)u) << 16;
  return __uint_as_float(x);
}
static __device__ __forceinline__ unsigned short f2bf(float f){
  unsigned int x = __float_as_uint(f);
  unsigned int r = (x + 0x7fffu + ((x >> 16) & 1u)) >> 16;
  return (unsigned short)r;
}
static __device__ __forceinline__ void addv(float* acc, us8 v){
  #pragma unroll
  for (int k = 0; k < 8; k++) acc[k] += bf2f(v[k]);
}
// fp8 e4m3fn encode: RNE, saturate 448, denormals handled
static __device__ __forceinline__ unsigned char f2fp8(float f){
  unsigned int u = __float_as_uint(f);
  unsigned int s = (u >> 24) & 0x80u;
  float av = fabsf(f);
  if (av >= 448.f) return (unsigned char)(s | 0x7Eu);
  if (av < 0.015625f){
    int m = (int)(av * 512.0f + 0.5f);
    return (unsigned char)(s | (unsigned)m);
  }
  unsigned int au = u & 0x7FFFFFFFu;
  unsigned int r = au + 0x7FFFFu + ((au >> 20) & 1u);
  return (unsigned char)(s | ((r >> 20) - 960u));
}
#if !__has_builtin(__builtin_amdgcn_cvt_pk_f32_fp8)
static __device__ __forceinline__ float fp8tof(unsigned char b){
  unsigned int s = ((unsigned int)(b & 0x80u)) << 24;
  unsigned int e = (b >> 3) & 0xFu, m = b & 7u;
  float v = (e == 0) ? ((float)m * 0.001953125f)
                     : __uint_as_float(((e + 120u) << 23) | (m << 20));
  return __uint_as_float(__float_as_uint(v) | s);
}
#endif
static __device__ __forceinline__ void addq(float* acc, uint2 v){
#if __has_builtin(__builtin_amdgcn_cvt_pk_f32_fp8)
  f32x2 p0 = __builtin_amdgcn_cvt_pk_f32_fp8((int)v.x, false);
  f32x2 p1 = __builtin_amdgcn_cvt_pk_f32_fp8((int)v.x, true);
  f32x2 p2 = __builtin_amdgcn_cvt_pk_f32_fp8((int)v.y, false);
  f32x2 p3 = __builtin_amdgcn_cvt_pk_f32_fp8((int)v.y, true);
  acc[0] += p0[0]; acc[1] += p0[1]; acc[2] += p1[0]; acc[3] += p1[1];
  acc[4] += p2[0]; acc[5] += p2[1]; acc[6] += p3[0]; acc[7] += p3[1];
#else
  unsigned int a = v.x, b = v.y;
  acc[0] += fp8tof(a & 0xFF);         acc[1] += fp8tof((a >> 8) & 0xFF);
  acc[2] += fp8tof((a >> 16) & 0xFF); acc[3] += fp8tof(a >> 24);
  acc[4] += fp8tof(b & 0xFF);         acc[5] += fp8tof((b >> 8) & 0xFF);
  acc[6] += fp8tof((b >> 16) & 0xFF); acc[7] += fp8tof(b >> 24);
#endif
}
static __device__ __forceinline__ void gld16(const void* g, void* l){
  __builtin_amdgcn_global_load_lds((const __attribute__((address_space(1))) void*)g,
                                   (__attribute__((address_space(3))) void*)l, 16, 0, 0);
}

// ---------------- Fused: degree || cvt || prep_w (all independent) ----------------

__global__ __launch_bounds__(256)
void k_dc(const int* __restrict__ dst, int* __restrict__ cnt,
          const float* __restrict__ x, unsigned short* __restrict__ xb,
          const float* __restrict__ W1l, const float* __restrict__ W1r,
          const float* __restrict__ W2l, const float* __restrict__ W2r,
          unsigned short* __restrict__ Bt1, unsigned short* __restrict__ Bt2)
{
  const int bid = blockIdx.x, t = threadIdx.x;
  int role, idx;
  if (bid < 2 * NDB){
    role = bid & 1;               // 1=degree, 0=cvt (interleaved -> concurrent)
    idx = bid >> 1;
  } else if (bid < NDB + NCB){
    role = 0; idx = bid - NDB;
  } else {
    role = 2; idx = bid - NDB - NCB;
  }

  if (role == 1){
    int e = idx * 256 + t;
    if (e < NE) atomicAdd(&cnt[dst[e]], 1);
  } else if (role == 0){
    size_t i = ((size_t)idx * 256 + t) * 8;
    if (i >= (size_t)MPAD * 256) return;
    int row = (int)(i >> 8);
    us8 o;
    if (row < NN){
      const float4* p = (const float4*)(x + i);
      float4 a = p[0], b = p[1];
      o[0]=f2bf(a.x); o[1]=f2bf(a.y); o[2]=f2bf(a.z); o[3]=f2bf(a.w);
      o[4]=f2bf(b.x); o[5]=f2bf(b.y); o[6]=f2bf(b.z); o[7]=f2bf(b.w);
    } else {
      #pragma unroll
      for (int j = 0; j < 8; j++) o[j] = 0;
    }
    *(us8*)(xb + i) = o;
  } else {
    int i = idx * 256 + t;
    if (i < 512 * 256){
      int n = i >> 8, k = i & 255;
      float v = (n < 256) ? W1l[k * 256 + n] : W1r[k * 256 + (n - 256)];
      Bt1[n * 256 + k] = f2bf(v);
    }
    if (i < 256 * 256){
      int n = i >> 8, k = i & 255;
      float v = (n < 128) ? W2l[k * 128 + n] : W2r[k * 128 + (n - 128)];
      Bt2[n * 256 + k] = f2bf(v);
    }
  }
}

// ---------------- CSR scan kernels ----------------

__global__ void k_chunk_sum(const int* __restrict__ cnt, int* __restrict__ partials, int N){
  __shared__ int sw[16];
  int b = blockIdx.x, t = threadIdx.x;
  int i = b * 1024 + t;
  int v = (i < N) ? cnt[i] : 0;
  #pragma unroll
  for (int off = 32; off; off >>= 1) v += __shfl_xor(v, off);
  int lane = t & 63, w = t >> 6;
  if (lane == 0) sw[w] = v;
  __syncthreads();
  if (t < 16){
    int s = sw[t];
    #pragma unroll
    for (int off = 8; off; off >>= 1) s += __shfl_xor(s, off);
    if (t == 0) partials[b] = s;
  }
}

__global__ void k_chunk_scan(const int* __restrict__ cnt, const int* __restrict__ partials,
                             int nchunk,
                             int* __restrict__ offs, int* __restrict__ cursor,
                             float* __restrict__ deginv, int N){
  __shared__ int sd[1024];
  __shared__ int sp[128];
  int b = blockIdx.x, t = threadIdx.x;
  if (t < 128) sp[t] = (t < b && t < nchunk) ? partials[t] : 0;
  int i = b * 1024 + t;
  int v = (i < N) ? cnt[i] : 0;
  sd[t] = v;
  __syncthreads();
  #pragma unroll
  for (int off = 64; off; off >>= 1){
    if (t < off) sp[t] += sp[t + off];
    __syncthreads();
  }
  for (int off = 1; off < 1024; off <<= 1){
    int x = (t >= off) ? sd[t - off] : 0;
    __syncthreads();
    sd[t] += x;
    __syncthreads();
  }
  if (i < N){
    int excl = sp[0] + sd[t] - v;
    offs[i] = excl;
    cursor[i] = excl;
    deginv[i] = (v > 0) ? (1.0f / (float)v) : 0.0f;
  }
}

// ---------------- Fused: XCD-partitioned CSR fill || GEMM layer 1 ----------------
// 64-thread blocks, interleaved mod 16 (8 gemm + 8 fill) -> both roles on all
// XCDs, gemm keeps idx&7 == bid&7 == XCD residue.
// Fill is dst-range partitioned by XCD residue r = bid&7: only edges with
// dst in [r*NRES,(r+1)*NRES) are processed -> csr lines + cursor atomics are
// single-XCD-owned (kills the 16x cross-XCD write amplification). Each
// residue class scans the full edge list (8x dst reads, L2/L3-cheap).

__global__ __launch_bounds__(64)
void k_fg(const unsigned short* __restrict__ A,
          const unsigned short* __restrict__ Bt,
          unsigned short* __restrict__ R1,
          unsigned char* __restrict__ Q8,
          const int* __restrict__ src, const int* __restrict__ dst,
          int* __restrict__ cursor, int* __restrict__ csr)
{
  __shared__ __align__(16) unsigned short lA[64 * 64];  // 8KB
  __shared__ __align__(16) unsigned short lB[64 * 64];  // 8KB
  const int bid = blockIdx.x;
  const int lane = threadIdx.x & 63;

  bool isg; int idx = 0, r = 0, c = 0;
  if (bid < 2 * NG1){
    if ((bid & 15) < 8){ isg = true;  idx = ((bid >> 4) << 3) + (bid & 7); }
    else               { isg = false; r = bid & 7; c = bid >> 4; }
  } else {
    int t2 = bid - 2 * NG1;          // 2*NG1 is a multiple of 8
    isg = false; r = t2 & 7; c = CINT + (t2 >> 3);
  }

  if (!isg){
    if (c < NCHK){
      int base = c * CSZ;
      #pragma unroll
      for (int w = 0; w < CSZ; w += 64){
        int e = base + w + lane;
        if (e < NE){
          int dn = dst[e];
          if ((unsigned)(dn - r * NRES) < (unsigned)NRES){
            int p = atomicAdd(&cursor[dn], 1);
            csr[p] = src[e];
          }
        }
      }
    }
    return;
  }

  // ---- gemm1 tile ----
  const int xcd = idx & 7, j = idx >> 3;
  const int mt  = xcd * (MTP64 / 8) + (j >> 3);
  if (mt >= MT64) return;
  const int nt  = j & 7;
  const int m0  = mt * 64;
  const int n0  = nt * 64;

  f32x4 acc[4][4] = {};
  const int srow = lane >> 3;
  const int sc   = (lane & 7) ^ ((lane >> 3) & 7);

  for (int kt = 0; kt < 4; ++kt){
    asm volatile("s_waitcnt lgkmcnt(0)" ::: "memory");
    #pragma unroll
    for (int s = 0; s < 8; ++s){
      int row = s * 8 + srow;
      gld16(A  + (size_t)(m0 + row) * 256 + kt * 64 + sc * 8, &lA[s * 512]);
      gld16(Bt + (size_t)(n0 + row) * 256 + kt * 64 + sc * 8, &lB[s * 512]);
    }
    asm volatile("s_waitcnt vmcnt(0)" ::: "memory");
    __builtin_amdgcn_sched_barrier(0);
    #pragma unroll
    for (int ks = 0; ks < 2; ++ks){
      bf16x8 av[4], bv[4];
      const int kc = ks * 4 + (lane >> 4);
      #pragma unroll
      for (int m = 0; m < 4; m++){
        int rr = m * 16 + (lane & 15);
        av[m] = *(const bf16x8*)&lA[rr * 64 + ((kc ^ (rr & 7)) << 3)];
      }
      #pragma unroll
      for (int n = 0; n < 4; n++){
        int cc = n * 16 + (lane & 15);
        bv[n] = *(const bf16x8*)&lB[cc * 64 + ((kc ^ (cc & 7)) << 3)];
      }
      #pragma unroll
      for (int m = 0; m < 4; m++)
        #pragma unroll
        for (int n = 0; n < 4; n++)
          acc[m][n] = __builtin_amdgcn_mfma_f32_16x16x32_bf16(av[m], bv[n], acc[m][n], 0, 0, 0);
    }
  }

  const int crow0 = m0 + (lane >> 4) * 4;
  const int ccol0 = n0 + (lane & 15);
  if (n0 < 256){
    #pragma unroll
    for (int m = 0; m < 4; m++){
      #pragma unroll
      for (int rr = 0; rr < 4; rr++){
        size_t rowoff = (size_t)(crow0 + m * 16 + rr) * 256;
        #pragma unroll
        for (int n = 0; n < 4; n++)
          Q8[rowoff + ccol0 + n * 16] = f2fp8(acc[m][n][rr]);
      }
    }
  } else {
    const int cbase = ccol0 - 256;
    #pragma unroll
    for (int m = 0; m < 4; m++){
      #pragma unroll
      for (int rr = 0; rr < 4; rr++){
        size_t rowoff = (size_t)(crow0 + m * 16 + rr) * 256;
        #pragma unroll
        for (int n = 0; n < 4; n++)
          R1[rowoff + cbase + n * 16] = f2bf(acc[m][n][rr]);
      }
    }
  }
}

// ---------------- GEMM layer 2 (single-wave, barrier-free) ----------------

template<int NTL2>
__global__ __launch_bounds__(64)
void k_gemm(const unsigned short* __restrict__ A,
            const unsigned short* __restrict__ Bt,
            unsigned short* __restrict__ C)
{
  const int bid = blockIdx.x;
  const int xcd = bid & 7, j = bid >> 3;
  const int mt  = xcd * (MTP64 / 8) + (j >> NTL2);
  if (mt >= MT64) return;
  const int nt  = j & ((1 << NTL2) - 1);
  const int m0  = mt * 64;
  const int n0  = nt * 64;
  const int Nout = 64 << NTL2;

  __shared__ __align__(16) unsigned short lA[64 * 64];
  __shared__ __align__(16) unsigned short lB[64 * 64];
  const int lane = threadIdx.x & 63;

  f32x4 acc[4][4] = {};
  const int srow = lane >> 3;
  const int sc   = (lane & 7) ^ ((lane >> 3) & 7);

  for (int kt = 0; kt < 4; ++kt){
    asm volatile("s_waitcnt lgkmcnt(0)" ::: "memory");
    #pragma unroll
    for (int s = 0; s < 8; ++s){
      int row = s * 8 + srow;
      gld16(A  + (size_t)(m0 + row) * 256 + kt * 64 + sc * 8, &lA[s * 512]);
      gld16(Bt + (size_t)(n0 + row) * 256 + kt * 64 + sc * 8, &lB[s * 512]);
    }
    asm volatile("s_waitcnt vmcnt(0)" ::: "memory");
    __builtin_amdgcn_sched_barrier(0);
    #pragma unroll
    for (int ks = 0; ks < 2; ++ks){
      bf16x8 av[4], bv[4];
      const int kc = ks * 4 + (lane >> 4);
      #pragma unroll
      for (int m = 0; m < 4; m++){
        int rr = m * 16 + (lane & 15);
        av[m] = *(const bf16x8*)&lA[rr * 64 + ((kc ^ (rr & 7)) << 3)];
      }
      #pragma unroll
      for (int n = 0; n < 4; n++){
        int cc = n * 16 + (lane & 15);
        bv[n] = *(const bf16x8*)&lB[cc * 64 + ((kc ^ (cc & 7)) << 3)];
      }
      #pragma unroll
      for (int m = 0; m < 4; m++)
        #pragma unroll
        for (int n = 0; n < 4; n++)
          acc[m][n] = __builtin_amdgcn_mfma_f32_16x16x32_bf16(av[m], bv[n], acc[m][n], 0, 0, 0);
    }
  }

  const int crow0 = m0 + (lane >> 4) * 4;
  const int ccol0 = n0 + (lane & 15);
  #pragma unroll
  for (int m = 0; m < 4; m++){
    #pragma unroll
    for (int rr = 0; rr < 4; rr++){
      size_t rowoff = (size_t)(crow0 + m * 16 + rr) * Nout;
      #pragma unroll
      for (int n = 0; n < 4; n++)
        C[rowoff + ccol0 + n * 16] = f2bf(acc[m][n][rr]);
    }
  }
}

// ---------------- Aggregation 1: h = relu(deginv*agg(q1_fp8) + r1 + b1) ----------------

__global__ void k_agg1(const unsigned char* __restrict__ Q8,
                       const unsigned short* __restrict__ R1,
                       const float* __restrict__ b1,
                       const int* __restrict__ offs, const int* __restrict__ cnt,
                       const float* __restrict__ deginv,
                       const int* __restrict__ csr,
                       unsigned short* __restrict__ h, int N)
{
  int wv = threadIdx.x >> 6, lane = threadIdx.x & 63;
  int n = blockIdx.x * 4 + wv;
  if (n >= N) return;
  int beg = offs[n], d = cnt[n];
  const int g = lane >> 5;
  const int cl = lane & 31;
  const unsigned char* Qb = Q8 + cl * 8;

  float acc[8];
  #pragma unroll
  for (int k = 0; k < 8; k++) acc[k] = 0.f;

  for (int w0 = 0; w0 < d; w0 += 64){
    int wlen = min(d - w0, 64);
    int idx = 0;
    if (lane < wlen) idx = csr[beg + w0 + lane];
    int nIter = (wlen + 15) >> 4;
    for (int t = 0; t < nIter; t++){
      int e0 = t * 16 + g;
      int s0 = __shfl(idx, e0);
      int s1 = __shfl(idx, e0 + 2);
      int s2 = __shfl(idx, e0 + 4);
      int s3 = __shfl(idx, e0 + 6);
      int s4 = __shfl(idx, e0 + 8);
      int s5 = __shfl(idx, e0 + 10);
      int s6 = __shfl(idx, e0 + 12);
      int s7 = __shfl(idx, e0 + 14);
      uint2 v0 = *(const uint2*)(Qb + (size_t)s0 * 256);
      uint2 v1 = *(const uint2*)(Qb + (size_t)s1 * 256);
      uint2 v2 = *(const uint2*)(Qb + (size_t)s2 * 256);
      uint2 v3 = *(const uint2*)(Qb + (size_t)s3 * 256);
      uint2 v4 = *(const uint2*)(Qb + (size_t)s4 * 256);
      uint2 v5 = *(const uint2*)(Qb + (size_t)s5 * 256);
      uint2 v6 = *(const uint2*)(Qb + (size_t)s6 * 256);
      uint2 v7 = *(const uint2*)(Qb + (size_t)s7 * 256);
      if (e0 < wlen)      addq(acc, v0);
      if (e0 + 2 < wlen)  addq(acc, v1);
      if (e0 + 4 < wlen)  addq(acc, v2);
      if (e0 + 6 < wlen)  addq(acc, v3);
      if (e0 + 8 < wlen)  addq(acc, v4);
      if (e0 + 10 < wlen) addq(acc, v5);
      if (e0 + 12 < wlen) addq(acc, v6);
      if (e0 + 14 < wlen) addq(acc, v7);
    }
  }
  #pragma unroll
  for (int k = 0; k < 8; k++) acc[k] += __shfl_xor(acc[k], 32);

  if (lane < 32){
    float di = deginv[n];
    us8 rv = *(const us8*)(R1 + (size_t)n * 256 + cl * 8);
    float4 b0 = *(const float4*)(b1 + cl * 8);
    float4 b4 = *(const float4*)(b1 + cl * 8 + 4);
    float bb[8] = {b0.x, b0.y, b0.z, b0.w, b4.x, b4.y, b4.z, b4.w};
    us8 o;
    #pragma unroll
    for (int k = 0; k < 8; k++)
      o[k] = f2bf(fmaxf(acc[k] * di + bf2f(rv[k]) + bb[k], 0.f));
    *(us8*)(h + (size_t)n * 256 + cl * 8) = o;
  }
}

// ---------------- Aggregation 2 + classifier + log_softmax (fused, bf16) ----------------

__global__ void k_agg2cls(const unsigned short* __restrict__ C2,
                          const float* __restrict__ b2,
                          const float* __restrict__ Wc,
                          const float* __restrict__ bc,
                          const int* __restrict__ offs, const int* __restrict__ cnt,
                          const float* __restrict__ deginv,
                          const int* __restrict__ csr,
                          float* __restrict__ out, int N)
{
  int wv = threadIdx.x >> 6, lane = threadIdx.x & 63;
  int n = blockIdx.x * 4 + wv;
  if (n >= N) return;
  int beg = offs[n], d = cnt[n];
  const int g = lane >> 4;
  const int cl = lane & 15;

  float acc[8];
  #pragma unroll
  for (int k = 0; k < 8; k++) acc[k] = 0.f;

  for (int w0 = 0; w0 < d; w0 += 64){
    int wlen = min(d - w0, 64);
    int idx = 0;
    if (lane < wlen) idx = csr[beg + w0 + lane];
    int nIter = (wlen + 31) >> 5;
    for (int t = 0; t < nIter; t++){
      int e0 = t * 32 + g;
      int s0 = __shfl(idx, e0);
      int s1 = __shfl(idx, e0 + 4);
      int s2 = __shfl(idx, e0 + 8);
      int s3 = __shfl(idx, e0 + 12);
      int s4 = __shfl(idx, e0 + 16);
      int s5 = __shfl(idx, e0 + 20);
      int s6 = __shfl(idx, e0 + 24);
      int s7 = __shfl(idx, e0 + 28);
      us8 v0 = *(const us8*)(C2 + (size_t)s0 * 256 + cl * 8);
      us8 v1 = *(const us8*)(C2 + (size_t)s1 * 256 + cl * 8);
      us8 v2 = *(const us8*)(C2 + (size_t)s2 * 256 + cl * 8);
      us8 v3 = *(const us8*)(C2 + (size_t)s3 * 256 + cl * 8);
      us8 v4 = *(const us8*)(C2 + (size_t)s4 * 256 + cl * 8);
      us8 v5 = *(const us8*)(C2 + (size_t)s5 * 256 + cl * 8);
      us8 v6 = *(const us8*)(C2 + (size_t)s6 * 256 + cl * 8);
      us8 v7 = *(const us8*)(C2 + (size_t)s7 * 256 + cl * 8);
      if (e0 < wlen)      addv(acc, v0);
      if (e0 + 4 < wlen)  addv(acc, v1);
      if (e0 + 8 < wlen)  addv(acc, v2);
      if (e0 + 12 < wlen) addv(acc, v3);
      if (e0 + 16 < wlen) addv(acc, v4);
      if (e0 + 20 < wlen) addv(acc, v5);
      if (e0 + 24 < wlen) addv(acc, v6);
      if (e0 + 28 < wlen) addv(acc, v7);
    }
  }
  #pragma unroll
  for (int k = 0; k < 8; k++){
    acc[k] += __shfl_xor(acc[k], 16);
    acc[k] += __shfl_xor(acc[k], 32);
  }

  float di = deginv[n];
  us8 rv = *(const us8*)(C2 + (size_t)n * 256 + 128 + cl * 8);
  float4 b0 = *(const float4*)(b2 + cl * 8);
  float4 b4 = *(const float4*)(b2 + cl * 8 + 4);
  float bb[8] = {b0.x, b0.y, b0.z, b0.w, b4.x, b4.y, b4.z, b4.w};
  float p0 = 0.f, p1 = 0.f;
  #pragma unroll
  for (int k = 0; k < 8; k += 2){
    float h0 = fmaxf(acc[k]     * di + bf2f(rv[k])     + bb[k],     0.f);
    float h1 = fmaxf(acc[k + 1] * di + bf2f(rv[k + 1]) + bb[k + 1], 0.f);
    float4 w = *(const float4*)(Wc + (cl * 8 + k) * 2);
    p0 += h0 * w.x + h1 * w.z;
    p1 += h0 * w.y + h1 * w.w;
  }
  #pragma unroll
  for (int off = 8; off; off >>= 1){
    p0 += __shfl_xor(p0, off);
    p1 += __shfl_xor(p1, off);
  }
  if (lane == 0){
    float z0 = p0 + bc[0], z1 = p1 + bc[1];
    float m = fmaxf(z0, z1);
    float lse = m + logf(expf(z0 - m) + expf(z1 - m));
    out[(size_t)n * 2 + 0] = z0 - lse;
    out[(size_t)n * 2 + 1] = z1 - lse;
  }
}

// ---------------- host launch ----------------

extern "C" void kernel_launch(void* const* d_in, const int* in_sizes, int n_in,
                              void* d_out, int out_size, void* d_ws, size_t ws_size,
                              hipStream_t stream)
{
  const float* x   = (const float*)d_in[0];
  const int*   ei  = (const int*)d_in[1];
  const float* W1l = (const float*)d_in[2];
  const float* W1r = (const float*)d_in[3];
  const float* b1  = (const float*)d_in[4];
  const float* W2l = (const float*)d_in[5];
  const float* W2r = (const float*)d_in[6];
  const float* b2  = (const float*)d_in[7];
  const float* Wc  = (const float*)d_in[8];
  const float* bc  = (const float*)d_in[9];
  float* out = (float*)d_out;

  const int N = NN, E = NE;
  const int* src = ei;
  const int* dst = ei + E;

  char* ws = (char*)d_ws;
  size_t off = 0;
  auto alloc = [&](size_t bytes) -> void* {
    void* p = ws + off;
    off += (bytes + 255) & ~(size_t)255;
    return p;
  };
  int*   cnt      = (int*)alloc((size_t)N * 4);
  int*   offs     = (int*)alloc((size_t)N * 4);
  int*   cursor   = (int*)alloc((size_t)N * 4);
  float* deginv   = (float*)alloc((size_t)N * 4);
  int*   partials = (int*)alloc(1024);
  int*   csr      = (int*)alloc((size_t)E * 4);
  unsigned short* Bt1 = (unsigned short*)alloc((size_t)512 * 256 * 2);
  unsigned short* Bt2 = (unsigned short*)alloc((size_t)256 * 256 * 2);
  unsigned short* xb  = (unsigned short*)alloc((size_t)MPAD * 256 * 2);
  unsigned char*  Q8  = (unsigned char*)alloc((size_t)MPAD * 256);
  unsigned short* R1  = (unsigned short*)alloc((size_t)MPAD * 256 * 2);

  unsigned short* h  = xb;   // alias: xb dead after gemm1
  unsigned short* C2 = R1;   // alias: R1 dead after agg1

  (void)in_sizes; (void)n_in; (void)out_size; (void)ws_size;

  hipMemsetAsync(cnt, 0, (size_t)N * 4, stream);

  // degree || cvt || prep_w
  k_dc<<<NDB + NCB + 512, 256, 0, stream>>>(dst, cnt, x, xb, W1l, W1r, W2l, W2r, Bt1, Bt2);

  int nchunk = (N + 1023) / 1024;
  k_chunk_sum<<<nchunk, 1024, 0, stream>>>(cnt, partials, N);
  k_chunk_scan<<<nchunk, 1024, 0, stream>>>(cnt, partials, nchunk, offs, cursor, deginv, N);

  // XCD-partitioned CSR fill || GEMM layer 1 (fused)
  {
    int ntail = 8 * (NCHK - CINT);       // tail fill blocks
    k_fg<<<2 * NG1 + ntail, 64, 0, stream>>>(xb, Bt1, R1, Q8, src, dst, cursor, csr);
  }

  k_agg1<<<N / 4, 256, 0, stream>>>(Q8, R1, b1, offs, cnt, deginv, csr, h, N);

  // layer 2
  k_gemm<2><<<MTP64 * 4, 64, 0, stream>>>(h, Bt2, C2);
  k_agg2cls<<<N / 4, 256, 0, stream>>>(C2, b2, Wc, bc, offs, cnt, deginv, csr, out, N);
}